// Round 17
// baseline (86.260 us; speedup 1.0000x reference)
//
#include <hip/hip_runtime.h>

typedef __bf16 bf16x8 __attribute__((ext_vector_type(8)));
typedef float  f32x4  __attribute__((ext_vector_type(4)));

__device__ __forceinline__ unsigned short f2bf(float f) {
    unsigned int u = __float_as_uint(f);
    u += 0x7FFF + ((u >> 16) & 1);          // RNE
    return (unsigned short)(u >> 16);
}
__device__ __forceinline__ unsigned int pk2bf(float a, float b) {
    return (unsigned int)f2bf(a) | ((unsigned int)f2bf(b) << 16);
}

#define GLD_LDS16(gptr, lptr) \
    __builtin_amdgcn_global_load_lds((const __attribute__((address_space(1))) void*)(gptr), \
                                     (__attribute__((address_space(3))) void*)(lptr), 16, 0, 0)

#define FWC 0                      // smallGEMM done-counter (target 64)
#define FMT(mt) (16 + 16 * (mt))   // per-mt finalize counters (target 2), 64B apart
#define NFLAGS (16 + 16 * 64)

// ---- r9-proven 64x64-tile bf16 GEMM body, BK=64, 32 KB LDS.
// C[m][n] = sum_k A[m][k]*Bt[n][k], K=512, ld=512.
// EPI=0: Cout=float[M][512]. EPI=1: Cout=bf16 [512][512] transposed (C^T).
template<int EPI>
__device__ __forceinline__ void gemm_tile(const unsigned short* __restrict__ A,
                                          const unsigned short* __restrict__ Bt,
                                          void* __restrict__ Cout,
                                          unsigned short* lds,   // 2*2*4096 ushorts
                                          int bm, int bn)
{
    const int tid  = threadIdx.x;
    const int lane = tid & 63;
    const int w    = tid >> 6;
    const int wm   = w >> 1, wn = w & 1;

    const int srow   = w * 16 + (lane >> 3);
    const int schunk = (lane & 7) ^ (lane >> 3);    // inverse-swizzle on SOURCE
    const unsigned short* gA0 = A  + (size_t)(bm + srow    ) * 512 + schunk * 8;
    const unsigned short* gA1 = A  + (size_t)(bm + srow + 8) * 512 + schunk * 8;
    const unsigned short* gB0 = Bt + (size_t)(bn + srow    ) * 512 + schunk * 8;
    const unsigned short* gB1 = Bt + (size_t)(bn + srow + 8) * 512 + schunk * 8;

    const int arow = lane & 15;
    const int kg   = lane >> 4;
    int offA[2][2], offB[2][2];
    #pragma unroll
    for (int f = 0; f < 2; ++f)
        #pragma unroll
        for (int kk = 0; kk < 2; ++kk) {
            offA[f][kk] = (wm * 32 + f * 16 + arow) * 128 + (((kk * 4 + kg) ^ (arow & 7)) << 4);
            offB[f][kk] = (wn * 32 + f * 16 + arow) * 128 + (((kk * 4 + kg) ^ (arow & 7)) << 4);
        }

    f32x4 acc[2][2] = {};

    auto stage = [&](int buf, int kt) {
        const int k0 = kt * 64;
        unsigned short* la = lds + buf * 8192;
        unsigned short* lb = la + 4096;
        GLD_LDS16(gA0 + k0, la + (w * 16 + 0) * 64);
        GLD_LDS16(gA1 + k0, la + (w * 16 + 8) * 64);
        GLD_LDS16(gB0 + k0, lb + (w * 16 + 0) * 64);
        GLD_LDS16(gB1 + k0, lb + (w * 16 + 8) * 64);
    };

    stage(0, 0);
    asm volatile("s_waitcnt vmcnt(0)" ::: "memory");
    __syncthreads();

    #pragma unroll
    for (int kt = 0; kt < 8; ++kt) {
        const int buf = kt & 1;
        if (kt < 7) stage(buf ^ 1, kt + 1);
        const char* la = (const char*)(lds + buf * 8192);
        const char* lb = la + 8192;
        #pragma unroll
        for (int kk = 0; kk < 2; ++kk) {
            bf16x8 a0 = *(const bf16x8*)(la + offA[0][kk]);
            bf16x8 a1 = *(const bf16x8*)(la + offA[1][kk]);
            bf16x8 b0 = *(const bf16x8*)(lb + offB[0][kk]);
            bf16x8 b1 = *(const bf16x8*)(lb + offB[1][kk]);
            acc[0][0] = __builtin_amdgcn_mfma_f32_16x16x32_bf16(a0, b0, acc[0][0], 0, 0, 0);
            acc[0][1] = __builtin_amdgcn_mfma_f32_16x16x32_bf16(a0, b1, acc[0][1], 0, 0, 0);
            acc[1][0] = __builtin_amdgcn_mfma_f32_16x16x32_bf16(a1, b0, acc[1][0], 0, 0, 0);
            acc[1][1] = __builtin_amdgcn_mfma_f32_16x16x32_bf16(a1, b1, acc[1][1], 0, 0, 0);
        }
        asm volatile("s_waitcnt vmcnt(0)" ::: "memory");
        __syncthreads();
    }

    #pragma unroll
    for (int fm = 0; fm < 2; ++fm)
        #pragma unroll
        for (int fn = 0; fn < 2; ++fn) {
            const int row0 = bm + wm * 32 + fm * 16 + kg * 4;
            const int col  = bn + wn * 32 + fn * 16 + arow;
            if (EPI == 0) {
                float* C = (float*)Cout;
                #pragma unroll
                for (int r = 0; r < 4; ++r)
                    C[(size_t)(row0 + r) * 512 + col] = acc[fm][fn][r];
            } else {
                unsigned short* C = (unsigned short*)Cout;   // C^T
                ushort4 pk;
                pk.x = f2bf(acc[fm][fn][0]);
                pk.y = f2bf(acc[fm][fn][1]);
                pk.z = f2bf(acc[fm][fn][2]);
                pk.w = f2bf(acc[fm][fn][3]);
                *(ushort4*)(&C[(size_t)col * 512 + row0]) = pk;
            }
        }
}

// K1: [0,64) wpT transpose; [64,128) wv convert; [128,256) partials (float2);
//     bid 256: zero flags
__global__ __launch_bounds__(256) void k1_prep_partial(
    const float* __restrict__ x, const float* __restrict__ w_attn,
    const float* __restrict__ w_proj,
    unsigned short* __restrict__ wv, unsigned short* __restrict__ wpT,
    float* __restrict__ part, int* __restrict__ flags)
{
    __shared__ float ls[64][65];
    const int bid = blockIdx.x, tid = threadIdx.x;

    if (bid < 64) {
        const int m0 = (bid >> 3) * 64;
        const int j0 = (bid & 7) * 64;
        const int rr = tid >> 4;
        const int c4 = (tid & 15) * 4;
        #pragma unroll
        for (int i = 0; i < 4; ++i) {
            float4 v = *(const float4*)(w_proj + (size_t)(m0 + rr + 16 * i) * 512 + j0 + c4);
            ls[rr + 16 * i][c4 + 0] = v.x;
            ls[rr + 16 * i][c4 + 1] = v.y;
            ls[rr + 16 * i][c4 + 2] = v.z;
            ls[rr + 16 * i][c4 + 3] = v.w;
        }
        __syncthreads();
        const int c    = tid >> 2;
        const int mgrp = (tid & 3) * 16;
        #pragma unroll
        for (int u = 0; u < 4; ++u) {
            const int m = mgrp + u * 4;
            ushort4 o;
            o.x = f2bf(ls[m + 0][c]);
            o.y = f2bf(ls[m + 1][c]);
            o.z = f2bf(ls[m + 2][c]);
            o.w = f2bf(ls[m + 3][c]);
            *(ushort4*)(wpT + (size_t)(j0 + c) * 512 + m0 + m) = o;
        }
    } else if (bid < 128) {
        const int bb = bid - 64;
        #pragma unroll
        for (int i = 0; i < 4; ++i) {
            const int flat = bb * 1024 + i * 256 + tid;
            const int ir = flat >> 7;
            const int m4 = (flat & 127) * 4;
            float4 v = *(const float4*)(w_attn + (size_t)ir * 1536 + 1024 + m4);
            ushort4 o;
            o.x = f2bf(v.x); o.y = f2bf(v.y); o.z = f2bf(v.z); o.w = f2bf(v.w);
            *(ushort4*)(wv + (size_t)ir * 512 + m4) = o;
        }
    } else if (bid < 256) {
        const int g  = bid - 128;             // 0..127: global 32-row chunk
        const int k0 = tid * 2;
        const float* p = x + (size_t)g * 32 * 512 + k0;
        float rx = 0.f, ry = 0.f;
        #pragma unroll 8
        for (int t = 0; t < 32; ++t) {
            float2 v = *(const float2*)(p + (size_t)t * 512);
            rx += v.x; ry += v.y;
        }
        *(float2*)(part + (size_t)g * 512 + k0) = make_float2(rx, ry);
    } else {
        for (int i = tid; i < NFLAGS; i += 256) flags[i] = 0;
    }
}

// K2 (merged): [0,64) smallGEMM -> wcT, flag FWC;
//              [64,192) finalize (float2) -> s16, flag FMT(mt);
//              [192,704) bigGEMM: spin on FWC==64 && FMT(mt)==2, then compute
__global__ __launch_bounds__(256, 4) void k2_merged(
    const float* __restrict__ x,
    const unsigned short* __restrict__ wv, const unsigned short* __restrict__ wpT,
    const float* __restrict__ part,
    unsigned short* __restrict__ wcT, unsigned short* __restrict__ s16,
    float* __restrict__ y, int* __restrict__ flags)
{
    __shared__ __align__(16) unsigned short lds[2 * 2 * 4096];   // 32 KB
    const int bid = blockIdx.x, tid = threadIdx.x;

    if (bid < 64) {
        gemm_tile<1>(wv, wpT, wcT, lds, (bid >> 3) * 64, (bid & 7) * 64);
        __threadfence();
        __syncthreads();
        if (tid == 0)
            __hip_atomic_fetch_add(&flags[FWC], 1, __ATOMIC_RELEASE, __HIP_MEMORY_SCOPE_AGENT);
    } else if (bid < 192) {
        const int g  = bid - 64;              // 0..127: global 32-row chunk
        const int b  = g >> 6, ch = g & 63;
        const int k0 = tid * 2;
        float rx = 0.f, ry = 0.f;
        #pragma unroll 8
        for (int cc = 0; cc < 63; ++cc) {
            float2 v = *(const float2*)(part + ((size_t)b * 64 + cc) * 512 + k0);
            rx += (cc < ch) ? v.x : 0.f;
            ry += (cc < ch) ? v.y : 0.f;
        }
        const float*    p = x   + (size_t)g * 32 * 512 + k0;
        unsigned short* q = s16 + (size_t)g * 32 * 512 + k0;
        #pragma unroll 8
        for (int t = 0; t < 32; ++t) {
            float2 v = *(const float2*)(p + (size_t)t * 512);
            rx += v.x; ry += v.y;
            const float inv = 1.0f / (float)(ch * 32 + t + 1);
            *(unsigned int*)(q + (size_t)t * 512) = pk2bf(rx * inv, ry * inv);
        }
        __threadfence();
        __syncthreads();
        if (tid == 0)
            __hip_atomic_fetch_add(&flags[FMT(g >> 1)], 1, __ATOMIC_RELEASE, __HIP_MEMORY_SCOPE_AGENT);
    } else {
        const int ii  = bid - 192;            // 0..511
        const int xcd = ii & 7, idx = ii >> 3;
        const int vy  = xcd * 8 + (idx >> 3); // m-tile 0..63
        const int vx  = idx & 7;              // n-tile 0..7
        if (tid == 0) {
            while (__hip_atomic_load(&flags[FWC], __ATOMIC_RELAXED, __HIP_MEMORY_SCOPE_AGENT) < 64)
                __builtin_amdgcn_s_sleep(2);
            while (__hip_atomic_load(&flags[FMT(vy)], __ATOMIC_RELAXED, __HIP_MEMORY_SCOPE_AGENT) < 2)
                __builtin_amdgcn_s_sleep(2);
        }
        __syncthreads();
        __threadfence();                      // acquire: invalidate stale lines before reads
        gemm_tile<0>(s16, wcT, y, lds, vy * 64, vx * 64);
    }
}

extern "C" void kernel_launch(void* const* d_in, const int* in_sizes, int n_in,
                              void* d_out, int out_size, void* d_ws, size_t ws_size,
                              hipStream_t stream)
{
    const float* x      = (const float*)d_in[0];   // (2,2048,512)
    const float* w_attn = (const float*)d_in[1];   // (512,1536); V = cols [1024,1536)
    const float* w_proj = (const float*)d_in[2];   // (512,512)
    float* y = (float*)d_out;

    unsigned short* wv  = (unsigned short*)d_ws;       // [512][512] bf16
    unsigned short* wpT = wv  + 512 * 512;             // [512][512] bf16 (w_proj^T)
    unsigned short* wcT = wpT + 512 * 512;             // [512][512] bf16 ((wv@wp)^T)
    unsigned short* s16 = wcT + 512 * 512;             // [4096][512] bf16
    float* part = (float*)(s16 + (size_t)4096 * 512);  // [128][512] f32
    int*   flags = (int*)(part + 128 * 512);           // NFLAGS ints

    k1_prep_partial<<<257, 256, 0, stream>>>(x, w_attn, w_proj, wv, wpT, part, flags);
    k2_merged<<<704, 256, 0, stream>>>(x, wv, wpT, part, wcT, s16, y, flags);
}